// Round 6
// baseline (543.804 us; speedup 1.0000x reference)
//
#include <hip/hip_runtime.h>
#include <hip/hip_bf16.h>
#include <cstdint>
#include <cstddef>
#include <type_traits>

typedef _Float16 half8 __attribute__((ext_vector_type(8)));
typedef _Float16 half4v __attribute__((ext_vector_type(4)));
typedef float float4v __attribute__((ext_vector_type(4)));

// ---------------- CSR build ----------------

__global__ void k_zero_int(int* __restrict__ p, int n) {
  int i = blockIdx.x * blockDim.x + threadIdx.x;
  if (i < n) p[i] = 0;
}

__global__ void k_count(const int* __restrict__ dst, int* __restrict__ cnt, int E) {
  int e = blockIdx.x * blockDim.x + threadIdx.x;
  if (e < E) atomicAdd(&cnt[dst[e]], 1);
}

// hierarchical exclusive scan: local (per-1024 block) -> sums -> fixup
__global__ __launch_bounds__(1024) void k_scan_local(const int* __restrict__ cnt,
                                                     int* __restrict__ rowp,
                                                     int* __restrict__ bsum, int n) {
  __shared__ int sm[1024];
  int tid = threadIdx.x;
  int i = blockIdx.x * 1024 + tid;
  int v = (i < n) ? cnt[i] : 0;
  sm[tid] = v;
  __syncthreads();
  for (int off = 1; off < 1024; off <<= 1) {
    int t = (tid >= off) ? sm[tid - off] : 0;
    __syncthreads();
    sm[tid] += t;
    __syncthreads();
  }
  if (i < n) rowp[i] = sm[tid] - v;  // exclusive (pre-fixup)
  if (tid == 1023) bsum[blockIdx.x] = sm[1023];
}

__global__ __launch_bounds__(1024) void k_scan_sums(int* __restrict__ bsum, int nb) {
  __shared__ int sm[1024];
  int tid = threadIdx.x;
  int v = (tid < nb) ? bsum[tid] : 0;
  sm[tid] = v;
  __syncthreads();
  for (int off = 1; off < 1024; off <<= 1) {
    int t = (tid >= off) ? sm[tid - off] : 0;
    __syncthreads();
    sm[tid] += t;
    __syncthreads();
  }
  if (tid < nb) bsum[tid] = sm[tid] - v;  // exclusive
}

// fixup + cursor copy + dinv, fused
__global__ void k_finalize(int* __restrict__ rowp, const int* __restrict__ bsum,
                           const int* __restrict__ cnt, int* __restrict__ cursor,
                           float* __restrict__ dinv, int n, int E) {
  int i = blockIdx.x * blockDim.x + threadIdx.x;
  if (i < n) {
    int v = rowp[i] + bsum[i >> 10];
    rowp[i] = v;
    cursor[i] = v;
    dinv[i] = rsqrtf((float)(cnt[i] + 1));  // +1 self loop
  }
  if (i == 0) rowp[n] = E;
}

__global__ void k_fill(const int* __restrict__ src, const int* __restrict__ dst,
                       int* __restrict__ cursor, int* __restrict__ csr_src, int E) {
  int e = blockIdx.x * blockDim.x + threadIdx.x;
  if (e < E) {
    int pos = atomicAdd(&cursor[dst[e]], 1);
    csr_src[pos] = src[e];
  }
}

// ---------------- fused weight convert+transpose (3 matrices in one launch) --------

__global__ void k_w_convert_all(const float* __restrict__ W1, const float* __restrict__ Wg1,
                                const float* __restrict__ Wg2, _Float16* __restrict__ W1t,
                                _Float16* __restrict__ Wg1t, _Float16* __restrict__ Wg2t,
                                int in_dim, int hid) {
  int idx = blockIdx.x * blockDim.x + threadIdx.x;
  int n1 = in_dim * hid;
  int n2 = hid * hid;
  if (idx < n1) {
    int n = idx / in_dim, k = idx - n * in_dim;
    W1t[idx] = (_Float16)W1[(size_t)k * hid + n];
  } else if (idx < n1 + n2) {
    int i2 = idx - n1;
    int n = i2 / hid, k = i2 - n * hid;
    Wg1t[i2] = (_Float16)Wg1[(size_t)k * hid + n];
  } else if (idx < n1 + 2 * n2) {
    int i2 = idx - n1 - n2;
    int n = i2 / hid, k = i2 - n * hid;
    Wg2t[i2] = (_Float16)Wg2[(size_t)k * hid + n];
  }
}

// ---------------- row-stream MFMA GEMM (N=256 fixed) ----------------
// out[M,256] = act(A[M,K_] @ Bt^T [+bias]) [*rowscale]; Bt fp16 [256,K_].
// Block = 4 waves x 32 rows = 128 rows, each wave computes 32x256 in registers.
// B staged in LDS per 128-wide K-chunk (2 barriers/chunk, no per-slab barrier);
// A-fragments load DIRECT global -> MFMA A-layout regs (A[m=lane&15][k=quad*8+j]),
// issued before the staging barrier so their latency hides behind B-staging.
// NOTE: no device lambdas (clang-22 frontend crash, round 3).

#define BSTR 136  // LDS row stride in halves (128 + 8 pad)

template <typename AT>
__device__ __forceinline__ half8 load_a_h8(const AT* __restrict__ p, bool ok) {
  half8 v = {};
  if (ok) {
    if constexpr (std::is_same_v<AT, float>) {
      float4 f0 = *(const float4*)p;
      float4 f1 = *(const float4*)(p + 4);
      v[0] = (_Float16)f0.x; v[1] = (_Float16)f0.y;
      v[2] = (_Float16)f0.z; v[3] = (_Float16)f0.w;
      v[4] = (_Float16)f1.x; v[5] = (_Float16)f1.y;
      v[6] = (_Float16)f1.z; v[7] = (_Float16)f1.w;
    } else {
      v = *(const half8*)p;
    }
  }
  return v;
}

template <typename AT, int K_, int RELU, int BIAS, int SCALE>
__global__ __launch_bounds__(256, 2) void k_gemm_rs(const AT* __restrict__ A,
                                                    const _Float16* __restrict__ Bt,
                                                    const float* __restrict__ bias,
                                                    const float* __restrict__ rowscale,
                                                    _Float16* __restrict__ out, int M) {
  constexpr int CK = 128;        // K-chunk staged in LDS
  constexpr int NCH = K_ / CK;
  __shared__ _Float16 Bs[256 * BSTR];  // 68 KB -> 2 blocks/CU

  const int tid = threadIdx.x;
  const int wave = tid >> 6;
  const int lane = tid & 63;
  const int quad = lane >> 4;
  const int l15 = lane & 15;
  const int wrow = blockIdx.x * 128 + wave * 32;

  const int r0 = wrow + l15, r1 = wrow + 16 + l15;
  const bool ok0 = r0 < M, ok1 = r1 < M;
  const AT* Ap0 = A + (size_t)r0 * K_ + quad * 8;
  const AT* Ap1 = A + (size_t)r1 * K_ + quad * 8;

  float4v acc[2][16];
#pragma unroll
  for (int i = 0; i < 2; ++i)
#pragma unroll
    for (int j = 0; j < 16; ++j) acc[i][j] = (float4v){0.f, 0.f, 0.f, 0.f};

  for (int ck = 0; ck < NCH; ++ck) {
    const int kbase = ck * CK;
    // A-fragments for this chunk: issue global loads FIRST (latency hides
    // behind the B staging below).
    half8 af0[4], af1[4];
#pragma unroll
    for (int s = 0; s < 4; ++s) {
      af0[s] = load_a_h8<AT>(Ap0 + kbase + s * 32, ok0);
      af1[s] = load_a_h8<AT>(Ap1 + kbase + s * 32, ok1);
    }
    __syncthreads();  // previous chunk fully consumed (no-op cost on ck=0)
    // stage B chunk: 256 rows x 128 halves; thread t covers granules t+256*it
#pragma unroll
    for (int it = 0; it < 16; ++it) {
      int i = tid + it * 256;
      int n = i >> 4, g = i & 15;
      *(half8*)(Bs + n * BSTR + g * 8) =
          *(const half8*)(Bt + (size_t)n * K_ + kbase + g * 8);
    }
    __syncthreads();
    // compute: 16 n-tiles x 4 k-slabs, B-frag reused for both rowgroups
#pragma unroll
    for (int j = 0; j < 16; ++j) {
#pragma unroll
      for (int s = 0; s < 4; ++s) {
        half8 bf = *(const half8*)(Bs + (j * 16 + l15) * BSTR + s * 32 + quad * 8);
        acc[0][j] = __builtin_amdgcn_mfma_f32_16x16x32_f16(af0[s], bf, acc[0][j], 0, 0, 0);
        acc[1][j] = __builtin_amdgcn_mfma_f32_16x16x32_f16(af1[s], bf, acc[1][j], 0, 0, 0);
      }
    }
  }

  // epilogue: C/D layout col=lane&15, row=quad*4+reg
  float rs[2][4];
#pragma unroll
  for (int rg = 0; rg < 2; ++rg)
#pragma unroll
    for (int reg = 0; reg < 4; ++reg) {
      int r = wrow + rg * 16 + quad * 4 + reg;
      rs[rg][reg] = (SCALE && r < M) ? rowscale[r] : 1.f;
    }
#pragma unroll
  for (int j = 0; j < 16; ++j) {
    int c = j * 16 + l15;
    float bv = BIAS ? bias[c] : 0.f;
#pragma unroll
    for (int rg = 0; rg < 2; ++rg) {
      int rbase = wrow + rg * 16 + quad * 4;
      float4v a = acc[rg][j];
#pragma unroll
      for (int reg = 0; reg < 4; ++reg) {
        int r = rbase + reg;
        if (r < M) {
          float v = a[reg] + bv;
          if (RELU) v = fmaxf(v, 0.f);
          if (SCALE) v *= rs[rg][reg];
          out[(size_t)r * 256 + c] = (_Float16)v;
        }
      }
    }
  }
}

// ---------------- fp32 tiled GEMM (tail): C = act(A @ B + bias) ----------------

template <int RELU, int BIAS>
__global__ __launch_bounds__(256) void k_gemm(const float* __restrict__ A,
                                              const float* __restrict__ B,
                                              const float* __restrict__ bias,
                                              float* __restrict__ C,
                                              int M, int N, int K) {
  __shared__ float As[16][68];
  __shared__ float Bs[16][68];
  const int bm = blockIdx.y * 64;
  const int bn = blockIdx.x * 64;
  const int tid = threadIdx.x;
  const int tr = (tid >> 4) << 2;
  const int tc = (tid & 15) << 2;
  const int lm  = tid >> 2;
  const int lk  = (tid & 3) << 2;
  const int lk2 = tid >> 4;
  const int ln  = (tid & 15) << 2;
  const bool arow_ok = (bm + lm) < M;
  const float* Aptr = A + (size_t)(bm + lm) * K + lk;
  const float* Bptr = B + (size_t)lk2 * N + bn + ln;
  float acc[4][4] = {};
  for (int k0 = 0; k0 < K; k0 += 16) {
    float4 a4 = make_float4(0.f, 0.f, 0.f, 0.f);
    if (arow_ok) a4 = *(const float4*)(Aptr + k0);
    float4 b4 = *(const float4*)(Bptr + (size_t)k0 * N);
    As[lk + 0][lm] = a4.x;
    As[lk + 1][lm] = a4.y;
    As[lk + 2][lm] = a4.z;
    As[lk + 3][lm] = a4.w;
    *(float4*)&Bs[lk2][ln] = b4;
    __syncthreads();
#pragma unroll
    for (int k = 0; k < 16; ++k) {
      float4 av = *(const float4*)&As[k][tr];
      float4 bv = *(const float4*)&Bs[k][tc];
      float a[4] = {av.x, av.y, av.z, av.w};
      float b[4] = {bv.x, bv.y, bv.z, bv.w};
#pragma unroll
      for (int i = 0; i < 4; ++i)
#pragma unroll
        for (int j = 0; j < 4; ++j) acc[i][j] += a[i] * b[j];
    }
    __syncthreads();
  }
  float bias_v[4] = {0.f, 0.f, 0.f, 0.f};
  if (BIAS) {
    float4 bb = *(const float4*)(bias + bn + tc);
    bias_v[0] = bb.x; bias_v[1] = bb.y; bias_v[2] = bb.z; bias_v[3] = bb.w;
  }
#pragma unroll
  for (int i = 0; i < 4; ++i) {
    int r = bm + tr + i;
    if (r < M) {
      float4 o;
      o.x = acc[i][0] + bias_v[0];
      o.y = acc[i][1] + bias_v[1];
      o.z = acc[i][2] + bias_v[2];
      o.w = acc[i][3] + bias_v[3];
      if (RELU) {
        o.x = fmaxf(o.x, 0.f); o.y = fmaxf(o.y, 0.f);
        o.z = fmaxf(o.z, 0.f); o.w = fmaxf(o.w, 0.f);
      }
      *(float4*)&C[(size_t)r * N + bn + tc] = o;
    }
  }
}

// ---------------- GCN aggregation (gather, one wave/node, 256 feats) ----------------
// t is PRE-SCALED: t'[i] = t[i]*dinv[i].  out[i] = (t'[i] + sum t'[src]) * dinv[i] + b

template <typename OT>
__global__ __launch_bounds__(256) void k_agg(const _Float16* __restrict__ t,
                                             const int* __restrict__ row_ptr,
                                             const int* __restrict__ csr_src,
                                             const float* __restrict__ dinv,
                                             const float* __restrict__ bias,
                                             OT* __restrict__ out, int n_nodes) {
  int w = (int)((blockIdx.x * 256 + threadIdx.x) >> 6);
  int lane = threadIdx.x & 63;
  if (w >= n_nodes) return;
  float di = dinv[w];
  half4v v = *(const half4v*)(t + (size_t)w * 256 + lane * 4);
  float ax = (float)v[0], ay = (float)v[1], az = (float)v[2], aw = (float)v[3];
  int e0 = row_ptr[w], e1 = row_ptr[w + 1];
  int e = e0;
  for (; e + 4 <= e1; e += 4) {
    int s0 = csr_src[e];
    int s1 = csr_src[e + 1];
    int s2 = csr_src[e + 2];
    int s3 = csr_src[e + 3];
    half4v u0 = *(const half4v*)(t + (size_t)s0 * 256 + lane * 4);
    half4v u1 = *(const half4v*)(t + (size_t)s1 * 256 + lane * 4);
    half4v u2 = *(const half4v*)(t + (size_t)s2 * 256 + lane * 4);
    half4v u3 = *(const half4v*)(t + (size_t)s3 * 256 + lane * 4);
    ax += (float)u0[0] + (float)u1[0] + (float)u2[0] + (float)u3[0];
    ay += (float)u0[1] + (float)u1[1] + (float)u2[1] + (float)u3[1];
    az += (float)u0[2] + (float)u1[2] + (float)u2[2] + (float)u3[2];
    aw += (float)u0[3] + (float)u1[3] + (float)u2[3] + (float)u3[3];
  }
  for (; e < e1; ++e) {
    int s = csr_src[e];
    half4v u = *(const half4v*)(t + (size_t)s * 256 + lane * 4);
    ax += (float)u[0]; ay += (float)u[1]; az += (float)u[2]; aw += (float)u[3];
  }
  const float4 b = ((const float4*)bias)[lane];
  if constexpr (std::is_same_v<OT, float>) {
    float4 o;
    o.x = ax * di + b.x; o.y = ay * di + b.y;
    o.z = az * di + b.z; o.w = aw * di + b.w;
    ((float4*)(out + (size_t)w * 256))[lane] = o;
  } else {
    half4v o;
    o[0] = (_Float16)(ax * di + b.x); o[1] = (_Float16)(ay * di + b.y);
    o[2] = (_Float16)(az * di + b.z); o[3] = (_Float16)(aw * di + b.w);
    *(half4v*)(out + (size_t)w * 256 + lane * 4) = o;
  }
}

// ---------------- classifier: out[M,2] = h[M,K] @ Wc[K,2] + bc ----------------

__global__ __launch_bounds__(256) void k_cls(const float* __restrict__ h,
                                             const float* __restrict__ Wc,
                                             const float* __restrict__ bc,
                                             float* __restrict__ out, int M, int K) {
  __shared__ float w[512];
  for (int i = threadIdx.x; i < 2 * K; i += 256) w[i] = Wc[i];
  __syncthreads();
  int i = blockIdx.x * 256 + threadIdx.x;
  if (i >= M) return;
  float a0 = bc[0], a1 = bc[1];
  const float* hr = h + (size_t)i * K;
  for (int k = 0; k < K; ++k) {
    float a = hr[k];
    a0 += a * w[2 * k];
    a1 += a * w[2 * k + 1];
  }
  out[2 * i] = a0;
  out[2 * i + 1] = a1;
}

// ---------------- launch ----------------

extern "C" void kernel_launch(void* const* d_in, const int* in_sizes, int n_in,
                              void* d_out, int out_size, void* d_ws, size_t ws_size,
                              hipStream_t stream) {
  const float* x   = (const float*)d_in[0];
  const int*   ei  = (const int*)d_in[1];
  const float* W1  = (const float*)d_in[2];
  const float* b1  = (const float*)d_in[3];
  const float* Wg1 = (const float*)d_in[4];
  const float* bg1 = (const float*)d_in[5];
  const float* Wg2 = (const float*)d_in[6];
  const float* bg2 = (const float*)d_in[7];
  const float* W2  = (const float*)d_in[8];
  const float* b2  = (const float*)d_in[9];
  const float* Wc  = (const float*)d_in[10];
  const float* bc  = (const float*)d_in[11];
  float* out = (float*)d_out;

  const int hid     = in_sizes[3];            // 256 (== NN of k_gemm_rs)
  const int in_dim  = in_sizes[2] / hid;      // 768
  const int out_dim = in_sizes[9];            // 128
  const int N       = in_sizes[0] / in_dim;   // 50000
  const int E       = in_sizes[1] / 2;        // 800000
  const int Batch   = out_size / 2;           // 1024

  const int* srcI = ei;
  const int* dstI = ei + E;

  char* ws = (char*)d_ws;
  size_t off = 0;
  auto alloc = [&](size_t bytes) -> void* {
    void* p = ws + off;
    off = (off + bytes + 255) & ~(size_t)255;
    return p;
  };
  _Float16* h0h  = (_Float16*)alloc((size_t)N * hid * 2);
  _Float16* t1h  = (_Float16*)alloc((size_t)N * hid * 2);   // pre-scaled by dinv
  _Float16* h1h  = (_Float16*)alloc((size_t)N * hid * 2);
  _Float16* t2h  = (_Float16*)alloc((size_t)N * hid * 2);   // pre-scaled by dinv
  _Float16* W1t  = (_Float16*)alloc((size_t)in_dim * hid * 2);
  _Float16* Wg1t = (_Float16*)alloc((size_t)hid * hid * 2);
  _Float16* Wg2t = (_Float16*)alloc((size_t)hid * hid * 2);
  float* agg2    = (float*)alloc((size_t)Batch * hid * 4);
  float* h3      = (float*)alloc((size_t)Batch * out_dim * 4);
  float* dinv    = (float*)alloc((size_t)N * 4);
  int*   cnt     = (int*)alloc((size_t)N * 4);
  int*   rowp    = (int*)alloc((size_t)(N + 1) * 4);
  int*   bsum    = (int*)alloc((size_t)1024 * 4);
  int*   cursor  = (int*)alloc((size_t)N * 4);
  int*   csrs    = (int*)alloc((size_t)E * 4);
  (void)ws_size; (void)n_in;

  dim3 blk(256);
  const int nb = (N + 1023) / 1024;

  // CSR + norm build
  k_zero_int<<<(N + 255) / 256, blk, 0, stream>>>(cnt, N);
  k_count<<<(E + 255) / 256, blk, 0, stream>>>(dstI, cnt, E);
  k_scan_local<<<nb, 1024, 0, stream>>>(cnt, rowp, bsum, N);
  k_scan_sums<<<1, 1024, 0, stream>>>(bsum, nb);
  k_finalize<<<(N + 255) / 256, blk, 0, stream>>>(rowp, bsum, cnt, cursor, dinv, N, E);
  k_fill<<<(E + 255) / 256, blk, 0, stream>>>(srcI, dstI, cursor, csrs, E);

  // fused weight convert + transpose (fp16)
  {
    int total = in_dim * hid + 2 * hid * hid;
    k_w_convert_all<<<(total + 255) / 256, blk, 0, stream>>>(W1, Wg1, Wg2, W1t, Wg1t, Wg2t, in_dim, hid);
  }

  const int gblocks = (N + 127) / 128;  // 391
  // h0 = relu(x @ W1 + b1)
  k_gemm_rs<float, 768, 1, 1, 0><<<gblocks, blk, 0, stream>>>(x, W1t, b1, nullptr, h0h, N);
  // t1' = (h0 @ Wg1) * dinv[row]
  k_gemm_rs<_Float16, 256, 0, 0, 1><<<gblocks, blk, 0, stream>>>(h0h, Wg1t, nullptr, dinv, t1h, N);
  // h1 = (t1'[i] + sum t1'[src]) * dinv[i] + bg1   (fp16 out)
  k_agg<_Float16><<<(N + 3) / 4, blk, 0, stream>>>(t1h, rowp, csrs, dinv, bg1, h1h, N);
  // t2' = (h1 @ Wg2) * dinv[row]
  k_gemm_rs<_Float16, 256, 0, 0, 1><<<gblocks, blk, 0, stream>>>(h1h, Wg2t, nullptr, dinv, t2h, N);
  // conv2 aggregation only for rows [0, Batch)  (fp32 out)
  k_agg<float><<<(Batch + 3) / 4, blk, 0, stream>>>(t2h, rowp, csrs, dinv, bg2, agg2, Batch);
  // h3 = relu(agg2 @ W2 + b2)
  k_gemm<1, 1><<<dim3(out_dim / 64, (Batch + 63) / 64), blk, 0, stream>>>(agg2, W2, b2, h3, Batch, out_dim, hid);
  // logits = h3 @ Wc + bc
  k_cls<<<(Batch + 255) / 256, blk, 0, stream>>>(h3, Wc, bc, out, Batch, out_dim);
}